// Round 4
// baseline (126.486 us; speedup 1.0000x reference)
//
#include <hip/hip_runtime.h>
#include <hip/hip_cooperative_groups.h>

namespace cg = cooperative_groups;

#define NUM_EMB 100000
#define DIM 128
#define TILE_E 32
#define NTILES (NUM_EMB / TILE_E)  // 3125
#define NCU 256

typedef float f32x4 __attribute__((ext_vector_type(4)));
typedef unsigned short u16x8 __attribute__((ext_vector_type(8)));

__device__ __forceinline__ unsigned short f32_to_bf16_rne(float f) {
  union { float f; unsigned int u; } c;
  c.f = f;
  unsigned int u = c.u;
  u += 0x7FFFu + ((u >> 16) & 1u);  // round-to-nearest-even
  return (unsigned short)(u >> 16);
}

__device__ __forceinline__ float bf16_to_f32(unsigned short h) {
  union { unsigned int u; float f; } c;
  c.u = ((unsigned int)h) << 16;
  return c.f;
}

// LDS tile: bf16, row stride DIM+8 u16 = 272B (16B-aligned rows; transposed
// b128 reads are 2-way bank aliased = free).
#define TSTRIDE (DIM + 8)

// ---- Phase 1 body: one 32-embedding tile -> WT[e][d] = bf16(W[d][e]+b[d]) ----
__device__ __forceinline__ void transpose_body(
    const float* __restrict__ W, const float* __restrict__ b,
    unsigned short* __restrict__ WT, unsigned short* tileb, int tl, int t) {
  const int e0 = tl * TILE_E;
#pragma unroll
  for (int k = 0; k < 4; ++k) {
    const int linear = k * 256 + t;  // 0..1023
    const int e4 = linear & 7;       // float4 slot in the 32-e span
    const int d = linear >> 3;       // 0..127
    const f32x4 v =
        *reinterpret_cast<const f32x4*>(&W[(size_t)d * NUM_EMB + e0 + e4 * 4]);
    const float bias = b[d];
    tileb[(e4 * 4 + 0) * TSTRIDE + d] = f32_to_bf16_rne(v.x + bias);
    tileb[(e4 * 4 + 1) * TSTRIDE + d] = f32_to_bf16_rne(v.y + bias);
    tileb[(e4 * 4 + 2) * TSTRIDE + d] = f32_to_bf16_rne(v.z + bias);
    tileb[(e4 * 4 + 3) * TSTRIDE + d] = f32_to_bf16_rne(v.w + bias);
  }
  __syncthreads();
#pragma unroll
  for (int k = 0; k < 2; ++k) {
    const int linear = k * 256 + t;  // 0..511
    const int e = linear >> 4;       // 0..31
    const int d0 = (linear & 15) * 8;
    const u16x8 o =
        *reinterpret_cast<const u16x8*>(&tileb[e * TSTRIDE + d0]);
    *reinterpret_cast<u16x8*>(&WT[(size_t)(e0 + e) * DIM + d0]) = o;
  }
  __syncthreads();
}

// ---- Phase 2 body: 4 rows per wave, 16 lanes x 16B per row ----
__device__ __forceinline__ void gather_body(
    const int* __restrict__ idx, const unsigned short* __restrict__ WT,
    float* __restrict__ out, int n_lookups, int wid, int nwaves, int lane) {
  const int sub = lane >> 4;   // row slot 0..3
  const int l16 = lane & 15;   // 16B chunk within row
  const int nchunks = (n_lookups + 3) >> 2;
  for (int c = wid; c < nchunks; c += nwaves) {
    const int n = c * 4 + sub;
    if (n < n_lookups) {
      const int e = idx[n];
      const u16x8 h =
          *reinterpret_cast<const u16x8*>(&WT[(size_t)e * DIM + l16 * 8]);
      f32x4 lo, hi;
      lo.x = bf16_to_f32(h[0]); lo.y = bf16_to_f32(h[1]);
      lo.z = bf16_to_f32(h[2]); lo.w = bf16_to_f32(h[3]);
      hi.x = bf16_to_f32(h[4]); hi.y = bf16_to_f32(h[5]);
      hi.z = bf16_to_f32(h[6]); hi.w = bf16_to_f32(h[7]);
      float* op = &out[(size_t)n * DIM + l16 * 8];
      __builtin_nontemporal_store(lo, reinterpret_cast<f32x4*>(op));
      __builtin_nontemporal_store(hi, reinterpret_cast<f32x4*>(op) + 1);
    }
  }
}

// ---- Fused cooperative kernel ----
__global__ __launch_bounds__(256) void fused_embed_kernel(
    const int* __restrict__ idx, const float* __restrict__ W,
    const float* __restrict__ b, unsigned short* __restrict__ WT,
    float* __restrict__ out, int n_lookups, int nblocks) {
  __shared__ unsigned short tileb[TILE_E * TSTRIDE];
  const int t = threadIdx.x;
  for (int tl = blockIdx.x; tl < NTILES; tl += nblocks)
    transpose_body(W, b, WT, tileb, tl, t);
  cg::this_grid().sync();
  gather_body(idx, WT, out, n_lookups, blockIdx.x * 4 + (t >> 6), nblocks * 4,
              t & 63);
}

// ---- Split fallbacks (if cooperative launch is rejected) ----
__global__ __launch_bounds__(256) void transpose_kernel(
    const float* __restrict__ W, const float* __restrict__ b,
    unsigned short* __restrict__ WT) {
  __shared__ unsigned short tileb[TILE_E * TSTRIDE];
  transpose_body(W, b, WT, tileb, blockIdx.x, threadIdx.x);
}

__global__ __launch_bounds__(256) void gather_kernel(
    const int* __restrict__ idx, const unsigned short* __restrict__ WT,
    float* __restrict__ out, int n_lookups) {
  gather_body(idx, WT, out, n_lookups, blockIdx.x * 4 + (threadIdx.x >> 6),
              gridDim.x * 4, threadIdx.x & 63);
}

// ---- Last-resort fallback (ws too small): direct scattered gather ----
__global__ __launch_bounds__(256) void direct_gather_kernel(
    const int* __restrict__ idx, const float* __restrict__ W,
    const float* __restrict__ b, float* __restrict__ out, long total) {
  long gid = (long)blockIdx.x * 256 + threadIdx.x;
  const long stride = (long)gridDim.x * 256;
  for (; gid < total; gid += stride) {
    const int d = (int)(gid & (DIM - 1));
    const long n = gid >> 7;
    out[gid] = W[(size_t)d * NUM_EMB + idx[n]] + b[d];
  }
}

extern "C" void kernel_launch(void* const* d_in, const int* in_sizes, int n_in,
                              void* d_out, int out_size, void* d_ws,
                              size_t ws_size, hipStream_t stream) {
  const int* idx = (const int*)d_in[0];    // [204800]
  const float* W = (const float*)d_in[1];  // [128][100000]
  const float* b = (const float*)d_in[2];  // [128]
  float* out = (float*)d_out;              // [204800][128] f32
  const int n_lookups = in_sizes[0];

  const size_t wt_bytes = (size_t)NUM_EMB * DIM * sizeof(unsigned short);
  if (ws_size < wt_bytes) {
    const long total = (long)n_lookups * DIM;
    int blocks = (int)((total + 255) / 256);
    if (blocks > 2048) blocks = 2048;
    direct_gather_kernel<<<blocks, 256, 0, stream>>>(idx, W, b, out, total);
    return;
  }

  unsigned short* WT = (unsigned short*)d_ws;

  int occ = 0;
  if (hipOccupancyMaxActiveBlocksPerMultiprocessor(&occ, fused_embed_kernel,
                                                   256, 0) != hipSuccess)
    occ = 0;
  bool coop_ok = false;
  if (occ > 0) {
    int nblocks = occ * NCU;
    if (nblocks > 2048) nblocks = 2048;
    // Balance phase 1: equal tile rounds per block.
    const int rounds = (NTILES + nblocks - 1) / nblocks;
    nblocks = (NTILES + rounds - 1) / rounds;
    int n_l = n_lookups;
    void* args[] = {(void*)&idx, (void*)&W,   (void*)&b,       (void*)&WT,
                    (void*)&out, (void*)&n_l, (void*)&nblocks};
    hipError_t err = hipLaunchCooperativeKernel(
        fused_embed_kernel, dim3(nblocks), dim3(256), args, 0, stream);
    if (err == hipSuccess)
      coop_ok = true;
    else
      (void)hipGetLastError();  // clear non-sticky launch error
  }
  if (!coop_ok) {
    transpose_kernel<<<NTILES, 256, 0, stream>>>(W, b, WT);
    gather_kernel<<<2048, 256, 0, stream>>>(idx, WT, out, n_lookups);
  }
}

// Round 5
// 43.371 us; speedup vs baseline: 2.9164x; 2.9164x over previous
//
#include <hip/hip_runtime.h>

#define NUM_EMB 100000
#define DIM 128
#define TILE_E 32

typedef float f32x4 __attribute__((ext_vector_type(4)));
typedef unsigned short u16x4 __attribute__((ext_vector_type(4)));
typedef unsigned short u16x8 __attribute__((ext_vector_type(8)));

__device__ __forceinline__ unsigned short f32_to_bf16_rne(float f) {
  union { float f; unsigned int u; } c;
  c.f = f;
  unsigned int u = c.u;
  u += 0x7FFFu + ((u >> 16) & 1u);  // round-to-nearest-even
  return (unsigned short)(u >> 16);
}

__device__ __forceinline__ float bf16_to_f32(unsigned short h) {
  union { unsigned int u; float f; } c;
  c.u = ((unsigned int)h) << 16;
  return c.f;
}

// Pass 1: WT[e][d] = bf16(W[d][e] + b[d])   (fused bias, bf16 scratch)
// W: [DIM][NUM_EMB] f32 row-major, WT: [NUM_EMB][DIM] bf16 row-major.
// grid = NUM_EMB/TILE_E = 3125 blocks, 256 threads.
__global__ __launch_bounds__(256) void transpose_bias_bf16_kernel(
    const float* __restrict__ W, const float* __restrict__ b,
    unsigned short* __restrict__ WT) {
  __shared__ float tile[TILE_E][DIM + 1];  // f32 tile, stride 129 dwords:
                                           // write <=2-way (free), read clean
  const int t = threadIdx.x;
  const int e0 = blockIdx.x * TILE_E;

  // Load phase: 128 d x 8 float4 of e. 8 lanes cover one 128B aligned segment
  // (400000 B row stride is 128B-aligned). NT: W lines are single-use here;
  // keep L2 for WT dirty lines.
#pragma unroll
  for (int k = 0; k < 4; ++k) {
    const int linear = k * 256 + t;  // 0..1023
    const int e4 = linear & 7;       // float4 slot within the 32-e span
    const int d = linear >> 3;       // 0..127
    const f32x4 v = __builtin_nontemporal_load(
        reinterpret_cast<const f32x4*>(&W[(size_t)d * NUM_EMB + e0 + e4 * 4]));
    const float bias = b[d];
    tile[e4 * 4 + 0][d] = v.x + bias;
    tile[e4 * 4 + 1][d] = v.y + bias;
    tile[e4 * 4 + 2][d] = v.z + bias;
    tile[e4 * 4 + 3][d] = v.w + bias;
  }
  __syncthreads();

  // Store phase: 32 e-rows x 16 chunks of 8 d = 512 u16x8 stores (16B each).
  // Cached (not NT): pass 2 rereads WT from L2/L3.
#pragma unroll
  for (int k = 0; k < 2; ++k) {
    const int linear = k * 256 + t;  // 0..511
    const int e = linear >> 4;       // 0..31
    const int d0 = (linear & 15) * 8;
    u16x8 o;
#pragma unroll
    for (int j = 0; j < 8; ++j) o[j] = f32_to_bf16_rne(tile[e][d0 + j]);
    *reinterpret_cast<u16x8*>(&WT[(size_t)(e0 + e) * DIM + d0]) = o;
  }
}

// Pass 2: out[n][:] = f32(WT[idx[n]][:]).
// 32 lanes/row: u16x4 (8B) read -> 256B/row; f32x4 NT store -> 512B/row.
// 32 rows per 256-thread block; wave's 2 groups cover adjacent rows
// (1KB contiguous store per wave instruction). Fully unrolled, no guard
// when n_lookups % 32 == 0.
template <bool GUARD>
__global__ __launch_bounds__(256) void gather_rows_bf16_kernel(
    const int* __restrict__ idx, const unsigned short* __restrict__ WT,
    float* __restrict__ out, int n_lookups) {
  const int t = threadIdx.x;
  const int g = t >> 5;   // group 0..7
  const int q = t & 31;   // 8B chunk within row
#pragma unroll
  for (int i = 0; i < 4; ++i) {
    const int n = blockIdx.x * 32 + i * 8 + g;
    if (GUARD && n >= n_lookups) return;
    const int e = idx[n];
    const u16x4 h =
        *reinterpret_cast<const u16x4*>(&WT[(size_t)e * DIM + q * 4]);
    f32x4 v;
    v.x = bf16_to_f32(h[0]);
    v.y = bf16_to_f32(h[1]);
    v.z = bf16_to_f32(h[2]);
    v.w = bf16_to_f32(h[3]);
    __builtin_nontemporal_store(
        v, reinterpret_cast<f32x4*>(&out[(size_t)n * DIM + q * 4]));
  }
}

// Fallback (ws too small): direct scattered gather, correct but slow.
__global__ __launch_bounds__(256) void direct_gather_kernel(
    const int* __restrict__ idx, const float* __restrict__ W,
    const float* __restrict__ b, float* __restrict__ out, long total) {
  long gid = (long)blockIdx.x * 256 + threadIdx.x;
  const long stride = (long)gridDim.x * 256;
  for (; gid < total; gid += stride) {
    const int d = (int)(gid & (DIM - 1));
    const long n = gid >> 7;
    out[gid] = W[(size_t)d * NUM_EMB + idx[n]] + b[d];
  }
}

extern "C" void kernel_launch(void* const* d_in, const int* in_sizes, int n_in,
                              void* d_out, int out_size, void* d_ws,
                              size_t ws_size, hipStream_t stream) {
  const int* idx = (const int*)d_in[0];    // [204800]
  const float* W = (const float*)d_in[1];  // [128][100000]
  const float* b = (const float*)d_in[2];  // [128]
  float* out = (float*)d_out;              // [204800][128] f32
  const int n_lookups = in_sizes[0];

  const size_t wt_bytes = (size_t)NUM_EMB * DIM * sizeof(unsigned short);
  if (ws_size >= wt_bytes) {
    unsigned short* WT = (unsigned short*)d_ws;
    transpose_bias_bf16_kernel<<<NUM_EMB / TILE_E, 256, 0, stream>>>(W, b, WT);
    if (n_lookups % 32 == 0) {
      gather_rows_bf16_kernel<false>
          <<<n_lookups / 32, 256, 0, stream>>>(idx, WT, out, n_lookups);
    } else {
      gather_rows_bf16_kernel<true>
          <<<(n_lookups + 31) / 32, 256, 0, stream>>>(idx, WT, out, n_lookups);
    }
  } else {
    const long total = (long)n_lookups * DIM;
    int blocks = (int)((total + 255) / 256);
    if (blocks > 2048) blocks = 2048;
    direct_gather_kernel<<<blocks, 256, 0, stream>>>(idx, W, b, out, total);
  }
}